// Round 1
// baseline (239.521 us; speedup 1.0000x reference)
//
#include <hip/hip_runtime.h>
#include <math.h>

#define BN 2
#define AN 16368
#define GN 24
#define CN 15

#define DEGR 0.017453292519943295f  // pi/180

// order-preserving float -> uint mapping (monotonic for all finite floats)
__device__ __forceinline__ unsigned int ford(float f) {
    unsigned int u = __float_as_uint(f);
    return (u & 0x80000000u) ? ~u : (u | 0x80000000u);
}

// Intersection area of two rotated rectangles via Sutherland-Hodgman clipping.
// Equivalent polygon to the reference's candidate-point + angle-sort method.
__device__ float rect_inter_area(
    float ax, float ay, float aw, float ah, float at,
    float bx, float by, float bw, float bh, float bt)
{
    const float lx[4] = {-0.5f, 0.5f, 0.5f, -0.5f};
    const float ly[4] = {-0.5f, -0.5f, 0.5f, 0.5f};
    float ca = cosf(at * DEGR), sa = sinf(at * DEGR);
    float cb = cosf(bt * DEGR), sb = sinf(bt * DEGR);
    float px[10], py[10], tx[10], ty[10];
    float qx[4], qy[4];
    int n = 4;
#pragma unroll
    for (int i = 0; i < 4; ++i) {
        px[i] = ax + lx[i]*aw*ca - ly[i]*ah*sa;
        py[i] = ay + lx[i]*aw*sa + ly[i]*ah*ca;
        qx[i] = bx + lx[i]*bw*cb - ly[i]*bh*sb;
        qy[i] = by + lx[i]*bw*sb + ly[i]*bh*cb;
    }
    // clip subject A by each edge of B (corners are CCW; inside = cross >= 0)
    for (int e = 0; e < 4 && n > 0; ++e) {
        float ex0 = qx[e], ey0 = qy[e];
        float ex1 = qx[(e+1)&3], ey1 = qy[(e+1)&3];
        float dx = ex1 - ex0, dy = ey1 - ey0;
        int m = 0;
        float spx = px[n-1], spy = py[n-1];
        float sprev = dx*(spy-ey0) - dy*(spx-ex0);
        for (int i = 0; i < n; ++i) {
            float cx_ = px[i], cy_ = py[i];
            float scur = dx*(cy_-ey0) - dy*(cx_-ex0);
            bool inC = (scur >= 0.f), inP = (sprev >= 0.f);
            if (inC != inP) {
                float t = sprev / (sprev - scur);
                tx[m] = spx + t*(cx_-spx);
                ty[m] = spy + t*(cy_-spy);
                ++m;
            }
            if (inC) { tx[m] = cx_; ty[m] = cy_; ++m; }
            spx = cx_; spy = cy_; sprev = scur;
        }
        n = m;
        for (int i = 0; i < n; ++i) { px[i] = tx[i]; py[i] = ty[i]; }
    }
    if (n < 3) return 0.f;
    float s2 = 0.f;
    for (int i = 0; i < n; ++i) {
        int j = (i+1 == n) ? 0 : i+1;
        s2 += px[i]*py[j] - py[i]*px[j];
    }
    return 0.5f * fabsf(s2);
}

__global__ void init_kernel(unsigned long long* __restrict__ gt_best,
                            float* __restrict__ acc)
{
    int i = threadIdx.x;
    if (i < BN*GN) gt_best[i] = 0ull;   // any real packed key is > 0
    if (i < BN*3)  acc[i] = 0.f;
}

__global__ void pair_kernel(const float* __restrict__ anchors,
                            const float* __restrict__ ann,
                            float* __restrict__ iou_max,
                            int* __restrict__ iou_arg,
                            unsigned long long* __restrict__ gt_best)
{
    int a = blockIdx.x*blockDim.x + threadIdx.x;
    int b = blockIdx.y;
    if (a >= AN) return;
    const float* an = anchors + ((size_t)b*AN + a)*5;
    float acx = an[0], acy = an[1], aw = an[2], ah = an[3], at = an[4];
    // min-area square of anchor
    float sqa = 0.5f*fmaxf(aw, ah);
    float ax0 = acx-sqa, ay0 = acy-sqa, ax1 = acx+sqa, ay1 = acy+sqa;
    float ar_a = (ax1-ax0)*(ay1-ay0);
    float best = -INFINITY; int barg = 0;
    for (int g = 0; g < GN; ++g) {
        const float* gt = ann + ((size_t)b*GN + g)*6;
        float gcx = gt[0], gcy = gt[1], gw = gt[2], gh = gt[3], gth = gt[4], lab = gt[5];
        float v;
        if (lab < 0.f) {
            v = -1.f;   // where(valid, ., -1)
        } else {
            float sg = 0.5f*fmaxf(gw, gh);
            float bx0 = gcx-sg, by0 = gcy-sg, bx1 = gcx+sg, by1 = gcy+sg;
            float iw = fmaxf(fminf(ax1,bx1) - fmaxf(ax0,bx0), 0.f);
            float ih = fmaxf(fminf(ay1,by1) - fmaxf(ay0,by0), 0.f);
            float inter = iw*ih;
            float ar_b = (bx1-bx0)*(by1-by0);
            float ind = inter / (ar_a + ar_b - inter + 1e-9f);
            if (ind >= 0.1f) {
                float ia = rect_inter_area(acx,acy,aw,ah,at, gcx,gcy,gw,gh,gth);
                v = ia / (aw*ah + gw*gh - ia + 1e-9f);
            } else {
                v = 0.f;  // where(indicator>=0.1, iou, 0)
            }
        }
        if (v > best) { best = v; barg = g; }   // first-max tie break (== jnp.argmax)
        // per-GT max over anchors, tie -> smallest anchor index
        unsigned long long key = ((unsigned long long)ford(v) << 32)
                               | (unsigned long long)(0xFFFFFFFFu - (unsigned)a);
        atomicMax(&gt_best[b*GN + g], key);
    }
    iou_max[(size_t)b*AN + a] = best;
    iou_arg[(size_t)b*AN + a] = barg;
}

__global__ void loss_kernel(const float* __restrict__ cls,
                            const float* __restrict__ reg,
                            const float* __restrict__ anchors,
                            const float* __restrict__ ann,
                            const float* __restrict__ iou_max,
                            const int* __restrict__ iou_arg,
                            const unsigned long long* __restrict__ gt_best,
                            float* __restrict__ acc /* [B][3]: cls,reg,npos */)
{
    int a = blockIdx.x*blockDim.x + threadIdx.x;
    int b = blockIdx.y;
    float cls_acc = 0.f, reg_acc = 0.f, posf = 0.f;
    if (a < AN) {
        size_t idx = (size_t)b*AN + a;
        float imax = iou_max[idx];
        int   ag   = iou_arg[idx];
        bool pos = (imax >= 0.5f);
        // force-assign: each valid GT whose best anchor-iou < 0.5 makes its
        // (first) argmax anchor positive
        const unsigned long long thr = ((unsigned long long)ford(0.5f)) << 32;
        for (int g = 0; g < GN; ++g) {
            float lab = ann[((size_t)b*GN + g)*6 + 5];
            if (lab < 0.f) continue;
            unsigned long long k = gt_best[b*GN + g];
            if (k < thr) {   // max_gt < 0.5
                unsigned best_a = 0xFFFFFFFFu - (unsigned)(k & 0xFFFFFFFFull);
                if (best_a == (unsigned)a) pos = true;
            }
        }
        const float* gt = ann + ((size_t)b*GN + ag)*6;  // assigned = ann[iou_argmax]
        int acls = (int)gt[5];
        bool neg = (imax < 0.4f);   // IOU_THRES - 0.1
        if (pos || neg) {
            const float* cp = cls + ((size_t)b*AN + a)*CN;
            for (int c = 0; c < CN; ++c) {
                float p = fminf(fmaxf(cp[c], 1e-4f), 1.f - 1e-4f);
                if (pos && c == acls) {           // tgt = 1
                    float om = 1.f - p;
                    cls_acc += 0.25f * om*om * (-logf(p + 1e-6f));
                } else {                          // tgt = 0
                    cls_acc += 0.75f * p*p * (-logf(1.f - p + 1e-6f));
                }
            }
        } // else tgt = -1 everywhere: masked to 0
        if (pos) {
            posf = 1.f;
            const float* anp = anchors + ((size_t)b*AN + a)*5;
            float ew = fmaxf(anp[2], 1.f), eh = fmaxf(anp[3], 1.f);
            float gw = fmaxf(gt[2], 1.f),  gh = fmaxf(gt[3], 1.f);
            float t0 = 10.f*(gt[0]-anp[0])/ew;
            float t1 = 10.f*(gt[1]-anp[1])/eh;
            float t2 = 5.f*logf(gw/ew);
            float t3 = 5.f*logf(gh/eh);
            float t4 = 15.f*(tanf(gt[4]*DEGR) - tanf(anp[4]*DEGR));
            float tt[5] = {t0,t1,t2,t3,t4};
            const float* rp = reg + ((size_t)b*AN + a)*5;
            const float BETA_ = 1.f/9.f;
#pragma unroll
            for (int k2 = 0; k2 < 5; ++k2) {
                float d = fabsf(rp[k2] - tt[k2]);
                reg_acc += (d < BETA_) ? 0.5f*d*d/BETA_ : (d - 0.5f*BETA_);
            }
        }
    }
    // block reduction, one atomicAdd per value per block
    __shared__ float s0[256], s1[256], s2[256];
    int t = threadIdx.x;
    s0[t] = cls_acc; s1[t] = reg_acc; s2[t] = posf;
    __syncthreads();
    for (int off = 128; off > 0; off >>= 1) {
        if (t < off) { s0[t] += s0[t+off]; s1[t] += s1[t+off]; s2[t] += s2[t+off]; }
        __syncthreads();
    }
    if (t == 0) {
        atomicAdd(&acc[b*3+0], s0[0]);
        atomicAdd(&acc[b*3+1], s1[0]);
        atomicAdd(&acc[b*3+2], s2[0]);
    }
}

__global__ void final_kernel(const float* __restrict__ acc, float* __restrict__ out)
{
    if (threadIdx.x == 0 && blockIdx.x == 0) {
        float cl = 0.f, rl = 0.f;
        for (int b = 0; b < BN; ++b) {
            float np = acc[b*3+2];
            float c = acc[b*3+0] / fmaxf(np, 1.f);
            float r = (np > 0.f) ? acc[b*3+1] / fmaxf(np*5.f, 1.f) : 0.f;
            cl += c; rl += r;
        }
        out[0] = cl * (1.f/(float)BN);
        out[1] = rl * (1.f/(float)BN);
    }
}

extern "C" void kernel_launch(void* const* d_in, const int* in_sizes, int n_in,
                              void* d_out, int out_size, void* d_ws, size_t ws_size,
                              hipStream_t stream)
{
    const float* cls     = (const float*)d_in[0];  // (B,A,C)
    const float* reg     = (const float*)d_in[1];  // (B,A,5)
    const float* anchors = (const float*)d_in[2];  // (B,A,5)
    const float* ann     = (const float*)d_in[3];  // (B,G,6)
    float* out = (float*)d_out;

    // workspace layout (8B-aligned first)
    unsigned long long* gt_best = (unsigned long long*)d_ws;                 // BN*GN*8 = 384 B
    float* acc     = (float*)((char*)d_ws + 512);                            // BN*3*4
    float* iou_max = (float*)((char*)d_ws + 1024);                           // BN*AN*4
    int*   iou_arg = (int*)  ((char*)d_ws + 1024 + (size_t)BN*AN*4);         // BN*AN*4

    hipLaunchKernelGGL(init_kernel, dim3(1), dim3(64), 0, stream, gt_best, acc);
    dim3 grid((AN + 255)/256, BN);
    hipLaunchKernelGGL(pair_kernel, grid, dim3(256), 0, stream,
                       anchors, ann, iou_max, iou_arg, gt_best);
    hipLaunchKernelGGL(loss_kernel, grid, dim3(256), 0, stream,
                       cls, reg, anchors, ann, iou_max, iou_arg, gt_best, acc);
    hipLaunchKernelGGL(final_kernel, dim3(1), dim3(1), 0, stream, acc, out);
}

// Round 2
// 44.158 us; speedup vs baseline: 5.4242x; 5.4242x over previous
//
#include <hip/hip_runtime.h>
#include <math.h>

#define BN 2
#define AN 16368
#define GN 24
#define CN 15

#define DEGR 0.017453292519943295f  // pi/180

typedef unsigned long long u64;

// order-preserving float -> uint mapping (monotonic for all finite floats)
__device__ __forceinline__ unsigned int ford(float f) {
    unsigned int u = __float_as_uint(f);
    return (u & 0x80000000u) ? ~u : (u | 0x80000000u);
}
__device__ __forceinline__ float ford_inv(unsigned int h) {
    return (h & 0x80000000u) ? __uint_as_float(h ^ 0x80000000u)
                             : __uint_as_float(~h);
}

// ---- streaming Sutherland-Hodgman: 4 chained clip stages -> shoelace ----
// No arrays, no runtime indexing: all state lives in registers.
struct AreaStage {
    float fx, fy, px, py, s;
    int n;
    __device__ __forceinline__ void reset() { s = 0.f; n = 0; }
    __device__ __forceinline__ void push(float x, float y) {
        if (n == 0) { fx = x; fy = y; }
        else s += px * y - py * x;
        px = x; py = y; ++n;
    }
    __device__ __forceinline__ void flush() { if (n) s += px * fy - py * fx; }
};

template <class Next>
struct ClipStage {
    float ex, ey, dx, dy;          // clip edge; inside = cross(d, v-e) >= 0
    float fx, fy, fs, px, py, ps;  // first / prev vertex + side
    int n;
    Next next;
    __device__ __forceinline__ void set_edge(float ex_, float ey_, float dx_, float dy_) {
        ex = ex_; ey = ey_; dx = dx_; dy = dy_; n = 0;
    }
    __device__ __forceinline__ void emit_edge(float x1, float y1, float s1) {
        bool in0 = (ps >= 0.f), in1 = (s1 >= 0.f);
        if (in0 != in1) {
            float t = ps / (ps - s1);
            next.push(px + t * (x1 - px), py + t * (y1 - py));
        }
        if (in1) next.push(x1, y1);
    }
    __device__ __forceinline__ void push(float x, float y) {
        float s = dx * (y - ey) - dy * (x - ex);
        if (n == 0) { fx = x; fy = y; fs = s; }
        else emit_edge(x, y, s);
        px = x; py = y; ps = s; ++n;
    }
    __device__ __forceinline__ void flush() {
        if (n) emit_edge(fx, fy, fs);
        next.flush();
    }
};

using Pipe = ClipStage<ClipStage<ClipStage<ClipStage<AreaStage>>>>;

// Intersection area of two rotated rects (same polygon as the array S-H,
// therefore numerically identical to the round-1 kernel that scored absmax 0).
__device__ float rect_inter_area(
    float ax, float ay, float aw, float ah, float at,
    float bx, float by, float bw, float bh, float bt)
{
    const float lx[4] = {-0.5f, 0.5f, 0.5f, -0.5f};
    const float ly[4] = {-0.5f, -0.5f, 0.5f, 0.5f};
    float ca = cosf(at * DEGR), sa = sinf(at * DEGR);
    float cb = cosf(bt * DEGR), sb = sinf(bt * DEGR);
    float qx[4], qy[4], axv[4], ayv[4];
#pragma unroll
    for (int i = 0; i < 4; ++i) {
        axv[i] = ax + lx[i]*aw*ca - ly[i]*ah*sa;
        ayv[i] = ay + lx[i]*aw*sa + ly[i]*ah*ca;
        qx[i]  = bx + lx[i]*bw*cb - ly[i]*bh*sb;
        qy[i]  = by + lx[i]*bw*sb + ly[i]*bh*cb;
    }
    Pipe p;
    p.set_edge(qx[0], qy[0], qx[1]-qx[0], qy[1]-qy[0]);
    p.next.set_edge(qx[1], qy[1], qx[2]-qx[1], qy[2]-qy[1]);
    p.next.next.set_edge(qx[2], qy[2], qx[3]-qx[2], qy[3]-qy[2]);
    p.next.next.next.set_edge(qx[3], qy[3], qx[0]-qx[3], qy[0]-qy[3]);
    p.next.next.next.next.reset();
#pragma unroll
    for (int i = 0; i < 4; ++i) p.push(axv[i], ayv[i]);
    p.flush();
    return 0.5f * fabsf(p.next.next.next.next.s);
}

// one thread per (anchor, gt) pair; grid = (ceil(A/256), G, B)
__global__ void pair_kernel(const float* __restrict__ anchors,
                            const float* __restrict__ ann,
                            u64* __restrict__ anchor_best,
                            u64* __restrict__ gt_best)
{
    int a = blockIdx.x * blockDim.x + threadIdx.x;
    int g = blockIdx.y;
    int b = blockIdx.z;
    float v = -2.f;
    if (a < AN) {
        const float* an = anchors + ((size_t)b*AN + a)*5;
        float acx = an[0], acy = an[1], aw = an[2], ah = an[3], at = an[4];
        const float* gt = ann + ((size_t)b*GN + g)*6;
        float gcx = gt[0], gcy = gt[1], gw = gt[2], gh = gt[3], gth = gt[4], lab = gt[5];
        if (lab < 0.f) {
            v = -1.f;  // where(valid, ., -1)
        } else {
            float sqa = 0.5f*fmaxf(aw, ah);
            float ax0 = acx-sqa, ay0 = acy-sqa, ax1 = acx+sqa, ay1 = acy+sqa;
            float sg = 0.5f*fmaxf(gw, gh);
            float bx0 = gcx-sg, by0 = gcy-sg, bx1 = gcx+sg, by1 = gcy+sg;
            float iw = fmaxf(fminf(ax1,bx1) - fmaxf(ax0,bx0), 0.f);
            float ih = fmaxf(fminf(ay1,by1) - fmaxf(ay0,by0), 0.f);
            float inter = iw*ih;
            float ar_a = (ax1-ax0)*(ay1-ay0);
            float ar_b = (bx1-bx0)*(by1-by0);
            float ind = inter / (ar_a + ar_b - inter + 1e-9f);
            if (ind >= 0.1f) {
                float ia = rect_inter_area(acx,acy,aw,ah,at, gcx,gcy,gw,gh,gth);
                v = ia / (aw*ah + gw*gh - ia + 1e-9f);
            } else {
                v = 0.f;  // where(indicator>=0.1, iou, 0)
            }
        }
        // per-anchor max over g; tie -> smallest g (== jnp.argmax first-max)
        u64 akey = ((u64)ford(v) << 32) | (u64)(0xFFFFFFFFu - (unsigned)g);
        atomicMax(&anchor_best[(size_t)b*AN + a], akey);
    }
    // per-GT max over anchors; tie -> smallest anchor index
    u64 gk = (a < AN)
        ? (((u64)ford(v) << 32) | (u64)(0xFFFFFFFFu - (unsigned)a))
        : 0ull;
    __shared__ u64 sm[256];
    int t = threadIdx.x;
    sm[t] = gk;
    __syncthreads();
    for (int off = 128; off > 0; off >>= 1) {
        if (t < off) sm[t] = (sm[t] > sm[t+off]) ? sm[t] : sm[t+off];
        __syncthreads();
    }
    if (t == 0) atomicMax(&gt_best[b*GN + g], sm[0]);
}

__global__ void loss_kernel(const float* __restrict__ cls,
                            const float* __restrict__ reg,
                            const float* __restrict__ anchors,
                            const float* __restrict__ ann,
                            const u64* __restrict__ anchor_best,
                            const u64* __restrict__ gt_best,
                            float* __restrict__ acc /* [B][3]: cls,reg,npos */)
{
    int a = blockIdx.x*blockDim.x + threadIdx.x;
    int b = blockIdx.y;
    float cls_acc = 0.f, reg_acc = 0.f, posf = 0.f;
    if (a < AN) {
        u64 key = anchor_best[(size_t)b*AN + a];
        float imax = ford_inv((unsigned)(key >> 32));
        int   ag   = (int)(0xFFFFFFFFu - (unsigned)(key & 0xFFFFFFFFull));
        bool pos = (imax >= 0.5f);
        // force-assign: each valid GT whose best anchor-iou < 0.5 makes its
        // (first) argmax anchor positive
        const u64 thr = ((u64)ford(0.5f)) << 32;
        for (int g = 0; g < GN; ++g) {
            float lab = ann[((size_t)b*GN + g)*6 + 5];
            if (lab < 0.f) continue;
            u64 k = gt_best[b*GN + g];
            if (k < thr) {
                unsigned best_a = 0xFFFFFFFFu - (unsigned)(k & 0xFFFFFFFFull);
                if (best_a == (unsigned)a) pos = true;
            }
        }
        const float* gt = ann + ((size_t)b*GN + ag)*6;  // assigned = ann[iou_argmax]
        int acls = (int)gt[5];
        bool neg = (imax < 0.4f);   // IOU_THRES - 0.1
        if (pos || neg) {
            const float* cp = cls + ((size_t)b*AN + a)*CN;
            for (int c = 0; c < CN; ++c) {
                float p = fminf(fmaxf(cp[c], 1e-4f), 1.f - 1e-4f);
                if (pos && c == acls) {           // tgt = 1
                    float om = 1.f - p;
                    cls_acc += 0.25f * om*om * (-logf(p + 1e-6f));
                } else {                          // tgt = 0
                    cls_acc += 0.75f * p*p * (-logf(1.f - p + 1e-6f));
                }
            }
        } // else tgt = -1 everywhere: masked to 0
        if (pos) {
            posf = 1.f;
            const float* anp = anchors + ((size_t)b*AN + a)*5;
            float ew = fmaxf(anp[2], 1.f), eh = fmaxf(anp[3], 1.f);
            float gw = fmaxf(gt[2], 1.f),  gh = fmaxf(gt[3], 1.f);
            float t0 = 10.f*(gt[0]-anp[0])/ew;
            float t1 = 10.f*(gt[1]-anp[1])/eh;
            float t2 = 5.f*logf(gw/ew);
            float t3 = 5.f*logf(gh/eh);
            float t4 = 15.f*(tanf(gt[4]*DEGR) - tanf(anp[4]*DEGR));
            float tt[5] = {t0,t1,t2,t3,t4};
            const float* rp = reg + ((size_t)b*AN + a)*5;
            const float BETA_ = 1.f/9.f;
#pragma unroll
            for (int k2 = 0; k2 < 5; ++k2) {
                float d = fabsf(rp[k2] - tt[k2]);
                reg_acc += (d < BETA_) ? 0.5f*d*d/BETA_ : (d - 0.5f*BETA_);
            }
        }
    }
    __shared__ float s0[256], s1[256], s2[256];
    int t = threadIdx.x;
    s0[t] = cls_acc; s1[t] = reg_acc; s2[t] = posf;
    __syncthreads();
    for (int off = 128; off > 0; off >>= 1) {
        if (t < off) { s0[t] += s0[t+off]; s1[t] += s1[t+off]; s2[t] += s2[t+off]; }
        __syncthreads();
    }
    if (t == 0) {
        atomicAdd(&acc[b*3+0], s0[0]);
        atomicAdd(&acc[b*3+1], s1[0]);
        atomicAdd(&acc[b*3+2], s2[0]);
    }
}

__global__ void final_kernel(const float* __restrict__ acc, float* __restrict__ out)
{
    if (threadIdx.x == 0 && blockIdx.x == 0) {
        float cl = 0.f, rl = 0.f;
        for (int b = 0; b < BN; ++b) {
            float np = acc[b*3+2];
            float c = acc[b*3+0] / fmaxf(np, 1.f);
            float r = (np > 0.f) ? acc[b*3+1] / fmaxf(np*5.f, 1.f) : 0.f;
            cl += c; rl += r;
        }
        out[0] = cl * (1.f/(float)BN);
        out[1] = rl * (1.f/(float)BN);
    }
}

extern "C" void kernel_launch(void* const* d_in, const int* in_sizes, int n_in,
                              void* d_out, int out_size, void* d_ws, size_t ws_size,
                              hipStream_t stream)
{
    const float* cls     = (const float*)d_in[0];  // (B,A,C)
    const float* reg     = (const float*)d_in[1];  // (B,A,5)
    const float* anchors = (const float*)d_in[2];  // (B,A,5)
    const float* ann     = (const float*)d_in[3];  // (B,G,6)
    float* out = (float*)d_out;

    // workspace layout
    u64*   gt_best     = (u64*)d_ws;                           // BN*GN*8 = 384 B
    float* acc         = (float*)((char*)d_ws + 512);          // BN*3*4  = 24 B
    u64*   anchor_best = (u64*)((char*)d_ws + 1024);           // BN*AN*8 = 261,888 B
    size_t ws_used = 1024 + (size_t)BN*AN*8;

    hipMemsetAsync(d_ws, 0, ws_used, stream);   // zero keys + acc (0 < any real key)

    dim3 pgrid((AN + 255)/256, GN, BN);
    hipLaunchKernelGGL(pair_kernel, pgrid, dim3(256), 0, stream,
                       anchors, ann, anchor_best, gt_best);

    dim3 lgrid((AN + 255)/256, BN);
    hipLaunchKernelGGL(loss_kernel, lgrid, dim3(256), 0, stream,
                       cls, reg, anchors, ann, anchor_best, gt_best, acc);

    hipLaunchKernelGGL(final_kernel, dim3(1), dim3(1), 0, stream, acc, out);
}